// Round 9
// baseline (163.394 us; speedup 1.0000x reference)
//
#include <hip/hip_runtime.h>
#include <cstdint>
#include <cstddef>

// GraphSAGE 2-layer + log_softmax — LDS-staged CSR build + bf16 MFMA.
// R23: R22 (best, 156.9us) + L2-resident two-phase gather in l1x.
// xq split into two 3.2MB half-feature tables (xqA feats 0-31, xqB 32-63),
// each fitting a 4MiB per-XCD L2. l1x gathers phase A then phase B over the
// SAME LDS-staged csr window (fixes R18's confounds: no second csr walk, no
// nt on index loads). Async-DMA batches now carry 8 edges per batch (2
// edges/slot: lane pairs load 16B halves of 32B rows) — 2x edges in flight,
// half the bytes per phase. Phase means held in registers (oA/oB) so the
// stage buffer stays live through phase B. Per-feature accumulation order
// unchanged (edges ascending) -> bit-identical numerics.
// finalk / csr_k frozen at R22; partprep emits xqA/xqB halves.
// Pipeline:
//   memset bcnt (512 ints)
//   K1 partprep_k: edges->buckets; x->bf16(xb)+fp8 halves(xqA,xqB); B-frags
//   K2 csr_k: per-bucket LDS counting sort -> csr + rowse
//   K3 l1x: LDS-window csr + 2-phase async-DMA gather (8 edges/batch)
//           -> bf16 mean; A=[mean|x] K=128; 16+4 mfma -> p,q
//   K4 finalk: LDS-window gather p (unroll x2); mean + q; 4-lane log_softmax

typedef float f32x4 __attribute__((ext_vector_type(4)));
typedef float f32x2 __attribute__((ext_vector_type(2)));
typedef short short8 __attribute__((ext_vector_type(8)));
typedef __bf16 bf16x8 __attribute__((ext_vector_type(8)));

#define BK 256     // nodes per coarse bucket
#define NBMAX 512  // bucket-count upper bound (scan width)
#define CAP 5120   // per-bucket edge capacity (avg 4092 for E=1.6M, +16 sigma)
#define TILE 8192  // edges per partition block
#define WCAP 512   // per-wave csr window capacity (16 nodes, mean 262 edges)

__device__ __forceinline__ unsigned f2bf(float f) {
    unsigned u = __float_as_uint(f);
    u += 0x7FFFu + ((u >> 16) & 1u);  // RNE
    return u >> 16;
}

__device__ __forceinline__ f32x4 mfma16(short8 a, short8 b, f32x4 c) {
    return __builtin_amdgcn_mfma_f32_16x16x32_bf16(
        __builtin_bit_cast(bf16x8, a), __builtin_bit_cast(bf16x8, b), c, 0, 0, 0);
}

// async 16B global->LDS DMA: per-lane global addr, LDS dest = base + lane*16
__device__ __forceinline__ void glds16(const void* g, void* l) {
    __builtin_amdgcn_global_load_lds(
        (const __attribute__((address_space(1))) unsigned int*)g,
        (__attribute__((address_space(3))) unsigned int*)l, 16, 0, 0);
}

// bf16-pair unpack-accumulate (hi half uses raw bits: <=2^-7 relative noise)
#define ACC2(r, alo, ahi)                     \
    alo += __uint_as_float((r) << 16);        \
    ahi += __uint_as_float(r);

// fp8-quad decode-accumulate: one uint = 4 e4m3 -> 4 fp32 via 2 hw cvt ops
#define ACCF8(w, i)                                                   \
    {                                                                 \
        f32x2 f0 = __builtin_amdgcn_cvt_pk_f32_fp8((w), false);       \
        f32x2 f1 = __builtin_amdgcn_cvt_pk_f32_fp8((w), true);        \
        acc[(i)] += f0.x; acc[(i) + 1] += f0.y;                       \
        acc[(i) + 2] += f1.x; acc[(i) + 3] += f1.y;                   \
    }

// ---- K1: merged coarse partition + x->bf16/fp8-halves + B-frag image ----
__global__ __launch_bounds__(512) void partprep_k(
    const int* __restrict__ ei, int* __restrict__ bcnt,
    unsigned* __restrict__ part, int E, int pblocks,
    const float* __restrict__ x, unsigned short* __restrict__ xb,
    unsigned char* __restrict__ xqA, unsigned char* __restrict__ xqB, int n,
    const float* __restrict__ W1l, const float* __restrict__ W1r,
    const float* __restrict__ W2l, const float* __restrict__ W2r,
    unsigned short* __restrict__ bimg, int xblocks) {
    __shared__ int scn[NBMAX], sbase[NBMAX], lofs[NBMAX], cur[NBMAX];  // 8 KB
    __shared__ unsigned stageW[TILE];         // 32 KB
    __shared__ unsigned short stageB[TILE];   // 16 KB
    int t = threadIdx.x;
    int bid = blockIdx.x;

    if (bid >= pblocks) {
        int cb = bid - pblocks;
        if (cb < xblocks) {  // ---- x -> bf16 + fp8 halves (512 thr x 8) ----
            int i = (cb * 512 + t) * 8;
            if (i >= n) return;
            const float4* xp = (const float4*)(x + i);
            float4 a = xp[0], b = xp[1];
            uint4 o;
            o.x = f2bf(a.x) | (f2bf(a.y) << 16);
            o.y = f2bf(a.z) | (f2bf(a.w) << 16);
            o.z = f2bf(b.x) | (f2bf(b.y) << 16);
            o.w = f2bf(b.z) | (f2bf(b.w) << 16);
            *(uint4*)(xb + i) = o;
            int w0 = __builtin_amdgcn_cvt_pk_fp8_f32(a.x, a.y, 0, false);
            w0 = __builtin_amdgcn_cvt_pk_fp8_f32(a.z, a.w, w0, true);
            int w1 = __builtin_amdgcn_cvt_pk_fp8_f32(b.x, b.y, 0, false);
            w1 = __builtin_amdgcn_cvt_pk_fp8_f32(b.z, b.w, w1, true);
            int node = i >> 6, feat = i & 63;
            unsigned char* dst = (feat < 32) ? (xqA + (size_t)node * 32 + feat)
                                             : (xqB + (size_t)node * 32 + (feat - 32));
            *(uint2*)dst = make_uint2((unsigned)w0, (unsigned)w1);
            return;
        }
        // ---- B-fragment image (3 blocks x 512 >= 1280 elements) ----
        int e = (cb - xblocks) * 512 + t;
        if (e >= 20 * 64) return;
        int f = e >> 6, L = e & 63;
        int qd = L >> 4, m = L & 15;
        unsigned o[8];
        if (f < 16) {
            int kb = f >> 2, nb = f & 3;
            int n2 = nb * 16 + m;
#pragma unroll
            for (int j = 0; j < 8; ++j) {
                int k = kb * 32 + qd * 8 + j;
                float v = (k < 64) ? W1l[k * 64 + n2] : W1r[(k - 64) * 64 + n2];
                o[j] = f2bf(v);
            }
        } else {
            int g = f - 16;
            int kb = g >> 1, nb = g & 1;
#pragma unroll
            for (int j = 0; j < 8; ++j) {
                int k = kb * 32 + qd * 8 + j;
                float v = nb ? W2r[k * 16 + m] : W2l[k * 16 + m];
                o[j] = f2bf(v);
            }
        }
        uint4 pk;
        pk.x = o[0] | (o[1] << 16);
        pk.y = o[2] | (o[3] << 16);
        pk.z = o[4] | (o[5] << 16);
        pk.w = o[6] | (o[7] << 16);
        ((uint4*)bimg)[e] = pk;
        return;
    }

    // ---- partition blocks: 512 thr x 16 edges, single-pass LDS ranking ----
    int base = bid * TILE;
    cur[t] = 0;
    __syncthreads();
    int4 s4[4], d4[4];
#pragma unroll
    for (int i = 0; i < 4; ++i) {
        int e0 = base + (t + i * 512) * 4;
        if (e0 < E) {  // E % 4 == 0 so whole int4 is valid
            s4[i] = ((const int4*)ei)[e0 >> 2];
            d4[i] = ((const int4*)(ei + E))[e0 >> 2];
        } else {
            d4[i] = make_int4(-1, -1, -1, -1);
            s4[i] = make_int4(0, 0, 0, 0);
        }
    }
    int rk[16];
#pragma unroll
    for (int i = 0; i < 4; ++i) {
        int d[4] = {d4[i].x, d4[i].y, d4[i].z, d4[i].w};
#pragma unroll
        for (int u = 0; u < 4; ++u)
            rk[i * 4 + u] = (d[u] >= 0) ? atomicAdd(&cur[d[u] >> 8], 1) : 0;
    }
    __syncthreads();
    int own = cur[t];
    scn[t] = own;
    __syncthreads();
    for (int off = 1; off < NBMAX; off <<= 1) {
        int v = (t >= off) ? scn[t - off] : 0;
        __syncthreads();
        scn[t] += v;
        __syncthreads();
    }
    lofs[t] = scn[t] - own;
    if (own > 0) sbase[t] = atomicAdd(&bcnt[t], own);  // reserve global space
    __syncthreads();
#pragma unroll
    for (int i = 0; i < 4; ++i) {
        int s[4] = {s4[i].x, s4[i].y, s4[i].z, s4[i].w};
        int d[4] = {d4[i].x, d4[i].y, d4[i].z, d4[i].w};
#pragma unroll
        for (int u = 0; u < 4; ++u) {
            if (d[u] < 0) continue;
            int b = d[u] >> 8;
            int pos = lofs[b] + rk[i * 4 + u];
            stageW[pos] = ((unsigned)(d[u] & (BK - 1)) << 17) | (unsigned)s[u];
            stageB[pos] = (unsigned short)b;
        }
    }
    __syncthreads();
    int tot = scn[NBMAX - 1];
    for (int q = t; q < tot; q += 512) {  // consecutive threads -> consecutive addrs
        int b = stageB[q];
        part[b * CAP + sbase[b] + (q - lofs[b])] = stageW[q];
    }
}

// ---- K2: per-bucket LDS counting sort (256 thr, 1 node/thread) ----
__global__ __launch_bounds__(256) void csr_k(const unsigned* __restrict__ part,
                                             const int* __restrict__ bcnt,
                                             int* __restrict__ csr,
                                             int2* __restrict__ rowse, int N) {
    __shared__ int h[BK];
    __shared__ int s[BK];
    int b = blockIdx.x, t = threadIdx.x;
    int cnt = bcnt[b];
    int base = b * CAP;
    h[t] = 0;
    __syncthreads();
    for (int q = t; q < cnt; q += 256)
        atomicAdd(&h[(part[base + q] >> 17) & (BK - 1)], 1);
    __syncthreads();
    int own = h[t];
    s[t] = own;
    __syncthreads();
    for (int off = 1; off < BK; off <<= 1) {
        int v = (t >= off) ? s[t - off] : 0;
        __syncthreads();
        s[t] += v;
        __syncthreads();
    }
    int excl = s[t] - own;
    int node = b * BK + t;
    if (node < N) rowse[node] = make_int2(base + excl, base + excl + own);
    __syncthreads();
    h[t] = excl;  // reuse as cursors
    __syncthreads();
    for (int q = t; q < cnt; q += 256) {
        unsigned w = part[base + q];
        int pos = atomicAdd(&h[(w >> 17) & (BK - 1)], 1);
        csr[base + pos] = (int)(w & 0x1FFFFu);
    }
}

// ---- K3: 2-phase L2-resident async gather + MFMA layer1+2 ----
__global__ __launch_bounds__(256, 6) void l1x(
    const unsigned short* __restrict__ xb,
    const unsigned char* __restrict__ xqA, const unsigned char* __restrict__ xqB,
    const int2* __restrict__ rowse, const int* __restrict__ csr,
    const unsigned short* __restrict__ bimg,
    const float* __restrict__ b1, const float* __restrict__ b2,
    unsigned short* __restrict__ p, float* __restrict__ q, int N) {
    // per-wave 4KB region: gather stage (4 slots x 1KB) during BOTH phases,
    // then mean/h rows after (phase means held in registers meanwhile).
    __shared__ __align__(16) unsigned char sbuf[4][4096];  // 16 KB
    __shared__ int wcsr[4][WCAP];                          // 8 KB
    int t = threadIdx.x;
    int wave = t >> 6, lane = t & 63;
    int nodebase = blockIdx.x * 64 + wave * 16;
    int grp = lane >> 2, sub = lane & 3;  // 16 node-groups x 4 feature-lanes
    int node = nodebase + grp;
    int2 be = (node < N) ? rowse[node] : make_int2(0, 0);

    // hoisted independent self-row loads (used only at the MFMA stage)
    int qd = lane >> 4, m = lane & 15;
    int mynode = nodebase + m;
    short8 afr2 = {0, 0, 0, 0, 0, 0, 0, 0};
    short8 afr3 = {0, 0, 0, 0, 0, 0, 0, 0};
    if (mynode < N) {
        afr2 = *(const short8*)(xb + ((size_t)mynode << 6) + qd * 8);
        afr3 = *(const short8*)(xb + ((size_t)mynode << 6) + 32 + qd * 8);
    }

    // ---- stage this wave's contiguous csr window into LDS (coalesced) ----
    int wstart = 0, wlen = 0;
    if (nodebase < N) {
        int ln = min(nodebase + 15, N - 1);
        wstart = rowse[nodebase].x;
        wlen = rowse[ln].y - wstart;
    }
    bool useLds = (wlen <= WCAP);
    if (useLds) {
        for (int i = lane; i < wlen; i += 64) wcsr[wave][i] = csr[wstart + i];
    }

    const int* wc = &wcsr[wave][0];
    unsigned char* stg = &sbuf[wave][0];
    int kbeg = be.x - wstart, kend = be.y - wstart;
    int pairsel = sub >> 1;  // which of the 2 edges in a slot
    int half = sub & 1;      // which 16B half of the 32B row
    int rbase = ((lane >> 2) << 6);  // group's 64B row-pair base within a slot
    float rd = 1.0f / fmaxf((float)(be.y - be.x), 1.0f);
    float acc[8];
    uint4 oA, oB;

    // ---- phase A: feats 0-31 from xqA (3.2MB, L2-resident) ----
#pragma unroll
    for (int i = 0; i < 8; ++i) acc[i] = 0.f;
    if (useLds) {
        int k = kbeg;
        while (__any(k < kend)) {
#pragma unroll
            for (int j = 0; j < 4; ++j) {
                int e = k + 2 * j + pairsel;
                if (e < kend) {
                    int src = wc[e];
                    glds16(xqA + ((size_t)src << 5) + (half << 4),
                           stg + j * 1024);
                }
            }
            asm volatile("s_waitcnt vmcnt(0)" ::: "memory");
#pragma unroll
            for (int j = 0; j < 4; ++j) {
                if (k + 2 * j < kend) {  // edge 1 of slot j
                    uint2 r = *(const uint2*)(stg + j * 1024 + rbase + sub * 8);
                    ACCF8(r.x, 0); ACCF8(r.y, 4);
                }
                if (k + 2 * j + 1 < kend) {  // edge 2 of slot j
                    uint2 r = *(const uint2*)(stg + j * 1024 + rbase + 32 + sub * 8);
                    ACCF8(r.x, 0); ACCF8(r.y, 4);
                }
            }
            k += 8;
        }
    } else {  // fallback: global (window overflow — statistically never)
        for (int k = be.x; k < be.y; ++k) {
            int s0 = csr[k];
            uint2 r = *(const uint2*)(xqA + ((size_t)s0 << 5) + (sub << 3));
            ACCF8(r.x, 0); ACCF8(r.y, 4);
        }
    }
    oA.x = f2bf(acc[0] * rd) | (f2bf(acc[1] * rd) << 16);
    oA.y = f2bf(acc[2] * rd) | (f2bf(acc[3] * rd) << 16);
    oA.z = f2bf(acc[4] * rd) | (f2bf(acc[5] * rd) << 16);
    oA.w = f2bf(acc[6] * rd) | (f2bf(acc[7] * rd) << 16);

    // ---- phase B: feats 32-63 from xqB ----
#pragma unroll
    for (int i = 0; i < 8; ++i) acc[i] = 0.f;
    if (useLds) {
        int k = kbeg;
        while (__any(k < kend)) {
#pragma unroll
            for (int j = 0; j < 4; ++j) {
                int e = k + 2 * j + pairsel;
                if (e < kend) {
                    int src = wc[e];
                    glds16(xqB + ((size_t)src << 5) + (half << 4),
                           stg + j * 1024);
                }
            }
            asm volatile("s_waitcnt vmcnt(0)" ::: "memory");
#pragma unroll
            for (int j = 0; j < 4; ++j) {
                if (k + 2 * j < kend) {
                    uint2 r = *(const uint2*)(stg + j * 1024 + rbase + sub * 8);
                    ACCF8(r.x, 0); ACCF8(r.y, 4);
                }
                if (k + 2 * j + 1 < kend) {
                    uint2 r = *(const uint2*)(stg + j * 1024 + rbase + 32 + sub * 8);
                    ACCF8(r.x, 0); ACCF8(r.y, 4);
                }
            }
            k += 8;
        }
    } else {
        for (int k = be.x; k < be.y; ++k) {
            int s0 = csr[k];
            uint2 r = *(const uint2*)(xqB + ((size_t)s0 << 5) + (sub << 3));
            ACCF8(r.x, 0); ACCF8(r.y, 4);
        }
    }
    oB.x = f2bf(acc[0] * rd) | (f2bf(acc[1] * rd) << 16);
    oB.y = f2bf(acc[2] * rd) | (f2bf(acc[3] * rd) << 16);
    oB.z = f2bf(acc[4] * rd) | (f2bf(acc[5] * rd) << 16);
    oB.w = f2bf(acc[6] * rd) | (f2bf(acc[7] * rd) << 16);

    // gather fully consumed: overlay mh on the stage region and write means
    unsigned short (*mh)[72] = (unsigned short (*)[72])stg;
    *(uint4*)&mh[grp][sub * 8] = oA;       // feats sub*8..+7
    *(uint4*)&mh[grp][32 + sub * 8] = oB;  // feats 32+sub*8..+7
    // same-wave LDS write->read: lockstep, lgkmcnt handled by compiler

    // ---- A fragments: [mean | x], K = 128 ----
    const short8* bfr = (const short8*)bimg;
    short8 afr0 = *(const short8*)&mh[m][qd * 8];
    short8 afr1 = *(const short8*)&mh[m][32 + qd * 8];

    // ---- layer 1: 4 col-blocks x 4 K-steps; h overwrites mean buffer ----
#pragma unroll
    for (int nb = 0; nb < 4; ++nb) {
        f32x4 c = {0.f, 0.f, 0.f, 0.f};
        c = mfma16(afr0, bfr[nb * 64 + lane], c);
        c = mfma16(afr1, bfr[(4 + nb) * 64 + lane], c);
        c = mfma16(afr2, bfr[(8 + nb) * 64 + lane], c);
        c = mfma16(afr3, bfr[(12 + nb) * 64 + lane], c);
        int col = nb * 16 + m;
        float bb = b1[col];
#pragma unroll
        for (int r = 0; r < 4; ++r) {
            float hv = fmaxf(c[r] + bb, 0.0f);
            mh[qd * 4 + r][col] = (unsigned short)f2bf(hv);
        }
    }

    // ---- layer 2 ----
    short8 ha0 = *(const short8*)&mh[m][qd * 8];
    short8 ha1 = *(const short8*)&mh[m][32 + qd * 8];
    f32x4 pc = {0.f, 0.f, 0.f, 0.f}, qc = {0.f, 0.f, 0.f, 0.f};
    pc = mfma16(ha0, bfr[16 * 64 + lane], pc);
    pc = mfma16(ha1, bfr[18 * 64 + lane], pc);
    qc = mfma16(ha0, bfr[17 * 64 + lane], qc);
    qc = mfma16(ha1, bfr[19 * 64 + lane], qc);
    float b2v = b2[m];
#pragma unroll
    for (int r = 0; r < 4; ++r) {
        int nd = nodebase + qd * 4 + r;
        if (nd < N) {
            p[(size_t)nd * 16 + m] = (unsigned short)f2bf(pc[r]);
            q[(size_t)nd * 16 + m] = qc[r] + b2v;
        }
    }
}

// ---- K4: LDS-window gather p + mean + add + 4-lane log_softmax ----
__global__ __launch_bounds__(256) void finalk(const unsigned short* __restrict__ p,
                                              const int2* __restrict__ rowse,
                                              const int* __restrict__ csr,
                                              float* q, int N) {  // q in/out
    __shared__ int wcsr[4][WCAP];  // 8 KB: per-wave csr windows
    int t = threadIdx.x;
    int wave = t >> 6, lane = t & 63;
    int grp = lane >> 2, sub = lane & 3;  // 16 node-groups x 4 feature-lanes
    int nodebase = blockIdx.x * 64 + wave * 16;
    int node = nodebase + grp;
    int2 be = (node < N) ? rowse[node] : make_int2(0, 0);

    // stage wave csr window (all lanes participate before any exit)
    int wstart = 0, wlen = 0;
    if (nodebase < N) {
        int ln = min(nodebase + 15, N - 1);
        wstart = rowse[nodebase].x;
        wlen = rowse[ln].y - wstart;
    }
    bool useLds = (wlen <= WCAP);
    if (useLds) {
        for (int i = lane; i < wlen; i += 64) wcsr[wave][i] = csr[wstart + i];
    }
    if (node >= N) return;  // whole 4-lane group exits together

    // hoist the independent self-term read above the gather (overlaps latency)
    float4 qv = ((const float4*)(q + ((size_t)node << 4)))[sub];
    float a0 = 0.f, a1 = 0.f, a2 = 0.f, a3 = 0.f;
    if (useLds) {
        const int* wc = &wcsr[wave][0];
        int k = be.x - wstart, kend = be.y - wstart;
        for (; k + 1 < kend; k += 2) {
            uint2 rA = *(const uint2*)(p + ((size_t)wc[k] << 4) + (sub << 2));
            uint2 rB = *(const uint2*)(p + ((size_t)wc[k + 1] << 4) + (sub << 2));
            ACC2(rA.x, a0, a1);  ACC2(rA.y, a2, a3);
            ACC2(rB.x, a0, a1);  ACC2(rB.y, a2, a3);
        }
        if (k < kend) {
            uint2 rA = *(const uint2*)(p + ((size_t)wc[k] << 4) + (sub << 2));
            ACC2(rA.x, a0, a1);  ACC2(rA.y, a2, a3);
        }
    } else {
        int k = be.x, kend = be.y;
        for (; k + 1 < kend; k += 2) {
            int s0 = csr[k], s1 = csr[k + 1];
            uint2 rA = *(const uint2*)(p + ((size_t)s0 << 4) + (sub << 2));
            uint2 rB = *(const uint2*)(p + ((size_t)s1 << 4) + (sub << 2));
            ACC2(rA.x, a0, a1);  ACC2(rA.y, a2, a3);
            ACC2(rB.x, a0, a1);  ACC2(rB.y, a2, a3);
        }
        if (k < kend) {
            int s0 = csr[k];
            uint2 rA = *(const uint2*)(p + ((size_t)s0 << 4) + (sub << 2));
            ACC2(rA.x, a0, a1);  ACC2(rA.y, a2, a3);
        }
    }
    float rd = 1.0f / fmaxf((float)(be.y - be.x), 1.0f);
    float4 v = {a0 * rd + qv.x, a1 * rd + qv.y, a2 * rd + qv.z, a3 * rd + qv.w};
    float mm = fmaxf(fmaxf(v.x, v.y), fmaxf(v.z, v.w));
    mm = fmaxf(mm, __shfl_xor(mm, 1));
    mm = fmaxf(mm, __shfl_xor(mm, 2));
    float s = __expf(v.x - mm) + __expf(v.y - mm) + __expf(v.z - mm) + __expf(v.w - mm);
    s += __shfl_xor(s, 1);
    s += __shfl_xor(s, 2);
    float ls = __logf(s);
    float4 o = {v.x - mm - ls, v.y - mm - ls, v.z - mm - ls, v.w - mm - ls};
    ((float4*)(q + ((size_t)node << 4)))[sub] = o;
}

extern "C" void kernel_launch(void* const* d_in, const int* in_sizes, int n_in,
                              void* d_out, int out_size, void* d_ws, size_t ws_size,
                              hipStream_t stream) {
    const float* x   = (const float*)d_in[0];
    const int* ei    = (const int*)d_in[1];
    const float* W1l = (const float*)d_in[2];
    const float* W1r = (const float*)d_in[3];
    const float* b1  = (const float*)d_in[4];
    const float* W2l = (const float*)d_in[5];
    const float* W2r = (const float*)d_in[6];
    const float* b2  = (const float*)d_in[7];
    const int N = in_sizes[0] / 64;
    const int E = in_sizes[1] / 2;
    const int nbk = (N + BK - 1) / BK;  // 391 for N=100000

    // workspace layout (NO overlays — partprep_k writes part/xq* concurrently):
    //   bcnt(2K) | rowse(N*8) | csr(nbk*CAP*4) | bimg(20K) | p(N*32) |
    //   part(nbk*CAP*4) | xb(N*128) | xqA(N*32) | xqB(N*32)   total ~39 MB
    int*  bcnt  = (int*)d_ws;                            // NBMAX ints
    int2* rowse = (int2*)(bcnt + NBMAX);                 // N
    int*  csr   = (int*)(rowse + N);                     // nbk*CAP
    unsigned short* bimg = (unsigned short*)(csr + (size_t)nbk * CAP);
    unsigned short* p    = bimg + 20 * 64 * 8;           // N*16
    unsigned* part = (unsigned*)(p + (size_t)N * 16);    // nbk*CAP
    unsigned short* xb = (unsigned short*)(part + (size_t)nbk * CAP);  // N*64
    unsigned char* xqA = (unsigned char*)(xb + (size_t)N * 64);        // N*32
    unsigned char* xqB = xqA + (size_t)N * 32;                         // N*32
    float* q = (float*)d_out;                            // N*16 (temp q, then out)

    hipMemsetAsync(bcnt, 0, NBMAX * sizeof(int), stream);

    const int pblocks = (E + TILE - 1) / TILE;
    const int xblocks = (N * 64 + 4095) / 4096;  // 512 thr x 8 elems
    partprep_k<<<pblocks + xblocks + 3, 512, 0, stream>>>(
        ei, bcnt, part, E, pblocks, x, xb, xqA, xqB, N * 64, W1l, W1r, W2l,
        W2r, bimg, xblocks);
    csr_k<<<nbk, 256, 0, stream>>>(part, bcnt, csr, rowse, N);
    l1x<<<(N + 63) / 64, 256, 0, stream>>>(xb, xqA, xqB, rowse, csr, bimg,
                                           b1, b2, p, q, N);
    finalk<<<(N + 63) / 64, 256, 0, stream>>>(p, rowse, csr, q, N);
}

// Round 10
// 155.690 us; speedup vs baseline: 1.0495x; 1.0495x over previous
//
#include <hip/hip_runtime.h>
#include <cstdint>
#include <cstddef>

// GraphSAGE 2-layer + log_softmax — LDS-staged CSR build + bf16 MFMA.
// R24: exact R22 artifact (best, 156.9us) + async-DMA batch gather ported
// to finalk. R23's L2-residency retry regressed (3rd falsification) — the
// random-line rate is service-point-invariant; only REQUEST DEPTH moves the
// gather kernels. finalk batches: 4 glds16/batch stage 8 edges/group (2
// edges per 1KB slot; lane pairs fetch 16B halves of 32B p rows), vmcnt(0),
// accumulate from LDS in ascending edge order -> bitwise-identical.
// l1x / partprep_k / csr_k byte-for-byte R22.
// Pipeline:
//   memset bcnt (512 ints)
//   K1 partprep_k (512thr): [0,pb) partition 8192-edge tiles into 391 coarse
//                 buckets; [pb,pb+xb) x->bf16(xb)+fp8(xq); [+3) B-frag image
//   K2 csr_k (256thr): per-bucket LDS counting sort -> csr + rowse
//   K3 l1x    : LDS-window csr + async-DMA gather xq fp8 (4 lanes/node,
//               4-deep batches) -> bf16 mean in LDS; A=[mean|x] K=128;
//               16 mfma (layer1) -> relu -> LDS -> 4 mfma (layer2) -> p,q
//   K4 finalk : LDS-window csr + async-DMA gather p (8 edges/group/batch);
//               mean + q; 4-lane log_softmax

typedef float f32x4 __attribute__((ext_vector_type(4)));
typedef float f32x2 __attribute__((ext_vector_type(2)));
typedef short short8 __attribute__((ext_vector_type(8)));
typedef __bf16 bf16x8 __attribute__((ext_vector_type(8)));

#define BK 256     // nodes per coarse bucket
#define NBMAX 512  // bucket-count upper bound (scan width)
#define CAP 5120   // per-bucket edge capacity (avg 4092 for E=1.6M, +16 sigma)
#define TILE 8192  // edges per partition block
#define WCAP 512   // per-wave csr window capacity (16 nodes, mean 262 edges)

__device__ __forceinline__ unsigned f2bf(float f) {
    unsigned u = __float_as_uint(f);
    u += 0x7FFFu + ((u >> 16) & 1u);  // RNE
    return u >> 16;
}

__device__ __forceinline__ f32x4 mfma16(short8 a, short8 b, f32x4 c) {
    return __builtin_amdgcn_mfma_f32_16x16x32_bf16(
        __builtin_bit_cast(bf16x8, a), __builtin_bit_cast(bf16x8, b), c, 0, 0, 0);
}

// async 16B global->LDS DMA: per-lane global addr, LDS dest = base + lane*16
__device__ __forceinline__ void glds16(const void* g, void* l) {
    __builtin_amdgcn_global_load_lds(
        (const __attribute__((address_space(1))) unsigned int*)g,
        (__attribute__((address_space(3))) unsigned int*)l, 16, 0, 0);
}

// bf16-pair unpack-accumulate (hi half uses raw bits: <=2^-7 relative noise)
#define ACC2(r, alo, ahi)                     \
    alo += __uint_as_float((r) << 16);        \
    ahi += __uint_as_float(r);

// fp8-quad decode-accumulate: one uint = 4 e4m3 -> 4 fp32 via 2 hw cvt ops
#define ACCF8(w, i)                                                   \
    {                                                                 \
        f32x2 f0 = __builtin_amdgcn_cvt_pk_f32_fp8((w), false);       \
        f32x2 f1 = __builtin_amdgcn_cvt_pk_f32_fp8((w), true);        \
        acc[(i)] += f0.x; acc[(i) + 1] += f0.y;                       \
        acc[(i) + 2] += f1.x; acc[(i) + 3] += f1.y;                   \
    }
#define ACCQ(v)                                                       \
    { ACCF8((v).x, 0); ACCF8((v).y, 4); ACCF8((v).z, 8); ACCF8((v).w, 12); }

// ---- K1: merged coarse partition + x->bf16/fp8 + B-fragment image ----
__global__ __launch_bounds__(512) void partprep_k(
    const int* __restrict__ ei, int* __restrict__ bcnt,
    unsigned* __restrict__ part, int E, int pblocks,
    const float* __restrict__ x, unsigned short* __restrict__ xb,
    unsigned char* __restrict__ xq, int n,
    const float* __restrict__ W1l, const float* __restrict__ W1r,
    const float* __restrict__ W2l, const float* __restrict__ W2r,
    unsigned short* __restrict__ bimg, int xblocks) {
    __shared__ int scn[NBMAX], sbase[NBMAX], lofs[NBMAX], cur[NBMAX];  // 8 KB
    __shared__ unsigned stageW[TILE];         // 32 KB
    __shared__ unsigned short stageB[TILE];   // 16 KB
    int t = threadIdx.x;
    int bid = blockIdx.x;

    if (bid >= pblocks) {
        int cb = bid - pblocks;
        if (cb < xblocks) {  // ---- x -> bf16 + fp8 (512 thr x 8 elems) ----
            int i = (cb * 512 + t) * 8;
            if (i >= n) return;
            const float4* xp = (const float4*)(x + i);
            float4 a = xp[0], b = xp[1];
            uint4 o;
            o.x = f2bf(a.x) | (f2bf(a.y) << 16);
            o.y = f2bf(a.z) | (f2bf(a.w) << 16);
            o.z = f2bf(b.x) | (f2bf(b.y) << 16);
            o.w = f2bf(b.z) | (f2bf(b.w) << 16);
            *(uint4*)(xb + i) = o;
            int w0 = __builtin_amdgcn_cvt_pk_fp8_f32(a.x, a.y, 0, false);
            w0 = __builtin_amdgcn_cvt_pk_fp8_f32(a.z, a.w, w0, true);
            int w1 = __builtin_amdgcn_cvt_pk_fp8_f32(b.x, b.y, 0, false);
            w1 = __builtin_amdgcn_cvt_pk_fp8_f32(b.z, b.w, w1, true);
            *(uint2*)(xq + i) = make_uint2((unsigned)w0, (unsigned)w1);
            return;
        }
        // ---- B-fragment image (3 blocks x 512 >= 1280 elements) ----
        int e = (cb - xblocks) * 512 + t;
        if (e >= 20 * 64) return;
        int f = e >> 6, L = e & 63;
        int qd = L >> 4, m = L & 15;
        unsigned o[8];
        if (f < 16) {
            int kb = f >> 2, nb = f & 3;
            int n2 = nb * 16 + m;
#pragma unroll
            for (int j = 0; j < 8; ++j) {
                int k = kb * 32 + qd * 8 + j;
                float v = (k < 64) ? W1l[k * 64 + n2] : W1r[(k - 64) * 64 + n2];
                o[j] = f2bf(v);
            }
        } else {
            int g = f - 16;
            int kb = g >> 1, nb = g & 1;
#pragma unroll
            for (int j = 0; j < 8; ++j) {
                int k = kb * 32 + qd * 8 + j;
                float v = nb ? W2r[k * 16 + m] : W2l[k * 16 + m];
                o[j] = f2bf(v);
            }
        }
        uint4 pk;
        pk.x = o[0] | (o[1] << 16);
        pk.y = o[2] | (o[3] << 16);
        pk.z = o[4] | (o[5] << 16);
        pk.w = o[6] | (o[7] << 16);
        ((uint4*)bimg)[e] = pk;
        return;
    }

    // ---- partition blocks: 512 thr x 16 edges, single-pass LDS ranking ----
    int base = bid * TILE;
    cur[t] = 0;
    __syncthreads();
    int4 s4[4], d4[4];
#pragma unroll
    for (int i = 0; i < 4; ++i) {
        int e0 = base + (t + i * 512) * 4;
        if (e0 < E) {  // E % 4 == 0 so whole int4 is valid
            s4[i] = ((const int4*)ei)[e0 >> 2];
            d4[i] = ((const int4*)(ei + E))[e0 >> 2];
        } else {
            d4[i] = make_int4(-1, -1, -1, -1);
            s4[i] = make_int4(0, 0, 0, 0);
        }
    }
    int rk[16];
#pragma unroll
    for (int i = 0; i < 4; ++i) {
        int d[4] = {d4[i].x, d4[i].y, d4[i].z, d4[i].w};
#pragma unroll
        for (int u = 0; u < 4; ++u)
            rk[i * 4 + u] = (d[u] >= 0) ? atomicAdd(&cur[d[u] >> 8], 1) : 0;
    }
    __syncthreads();
    int own = cur[t];
    scn[t] = own;
    __syncthreads();
    for (int off = 1; off < NBMAX; off <<= 1) {
        int v = (t >= off) ? scn[t - off] : 0;
        __syncthreads();
        scn[t] += v;
        __syncthreads();
    }
    lofs[t] = scn[t] - own;
    if (own > 0) sbase[t] = atomicAdd(&bcnt[t], own);  // reserve global space
    __syncthreads();
#pragma unroll
    for (int i = 0; i < 4; ++i) {
        int s[4] = {s4[i].x, s4[i].y, s4[i].z, s4[i].w};
        int d[4] = {d4[i].x, d4[i].y, d4[i].z, d4[i].w};
#pragma unroll
        for (int u = 0; u < 4; ++u) {
            if (d[u] < 0) continue;
            int b = d[u] >> 8;
            int pos = lofs[b] + rk[i * 4 + u];
            stageW[pos] = ((unsigned)(d[u] & (BK - 1)) << 17) | (unsigned)s[u];
            stageB[pos] = (unsigned short)b;
        }
    }
    __syncthreads();
    int tot = scn[NBMAX - 1];
    for (int q = t; q < tot; q += 512) {  // consecutive threads -> consecutive addrs
        int b = stageB[q];
        part[b * CAP + sbase[b] + (q - lofs[b])] = stageW[q];
    }
}

// ---- K2: per-bucket LDS counting sort (256 thr, 1 node/thread) ----
__global__ __launch_bounds__(256) void csr_k(const unsigned* __restrict__ part,
                                             const int* __restrict__ bcnt,
                                             int* __restrict__ csr,
                                             int2* __restrict__ rowse, int N) {
    __shared__ int h[BK];
    __shared__ int s[BK];
    int b = blockIdx.x, t = threadIdx.x;
    int cnt = bcnt[b];
    int base = b * CAP;
    h[t] = 0;
    __syncthreads();
    for (int q = t; q < cnt; q += 256)
        atomicAdd(&h[(part[base + q] >> 17) & (BK - 1)], 1);
    __syncthreads();
    int own = h[t];
    s[t] = own;
    __syncthreads();
    for (int off = 1; off < BK; off <<= 1) {
        int v = (t >= off) ? s[t - off] : 0;
        __syncthreads();
        s[t] += v;
        __syncthreads();
    }
    int excl = s[t] - own;
    int node = b * BK + t;
    if (node < N) rowse[node] = make_int2(base + excl, base + excl + own);
    __syncthreads();
    h[t] = excl;  // reuse as cursors
    __syncthreads();
    for (int q = t; q < cnt; q += 256) {
        unsigned w = part[base + q];
        int pos = atomicAdd(&h[(w >> 17) & (BK - 1)], 1);
        csr[base + pos] = (int)(w & 0x1FFFFu);
    }
}

// ---- K3: async-DMA gather + MFMA layer1+2 (wave = 16 nodes) ----
__global__ __launch_bounds__(256, 6) void l1x(
    const unsigned short* __restrict__ xb, const unsigned char* __restrict__ xq,
    const int2* __restrict__ rowse, const int* __restrict__ csr,
    const unsigned short* __restrict__ bimg,
    const float* __restrict__ b1, const float* __restrict__ b2,
    unsigned short* __restrict__ p, float* __restrict__ q, int N) {
    // per-wave 4KB region: gather stage (4 slots x 1KB) during the gather,
    // then mean/h rows (16x72 shorts = 2304B) after — sequential same-wave
    // reuse, no cross-wave hazard.
    __shared__ __align__(16) unsigned char sbuf[4][4096];  // 16 KB
    __shared__ int wcsr[4][WCAP];                          // 8 KB
    int t = threadIdx.x;
    int wave = t >> 6, lane = t & 63;
    int nodebase = blockIdx.x * 64 + wave * 16;
    int grp = lane >> 2, sub = lane & 3;  // 16 node-groups x 4 feature-lanes
    int node = nodebase + grp;
    int2 be = (node < N) ? rowse[node] : make_int2(0, 0);

    // hoisted independent self-row loads (used only at the MFMA stage)
    int qd = lane >> 4, m = lane & 15;
    int mynode = nodebase + m;
    short8 afr2 = {0, 0, 0, 0, 0, 0, 0, 0};
    short8 afr3 = {0, 0, 0, 0, 0, 0, 0, 0};
    if (mynode < N) {
        afr2 = *(const short8*)(xb + ((size_t)mynode << 6) + qd * 8);
        afr3 = *(const short8*)(xb + ((size_t)mynode << 6) + 32 + qd * 8);
    }

    // ---- stage this wave's contiguous csr window into LDS (coalesced) ----
    int wstart = 0, wlen = 0;
    if (nodebase < N) {
        int ln = min(nodebase + 15, N - 1);
        wstart = rowse[nodebase].x;
        wlen = rowse[ln].y - wstart;
    }
    bool useLds = (wlen <= WCAP);
    if (useLds) {
        for (int i = lane; i < wlen; i += 64) wcsr[wave][i] = csr[wstart + i];
    }

    // lane sub accumulates features sub*16 .. sub*16+15 (one uint4 of fp8/edge)
    float acc[16];
#pragma unroll
    for (int i = 0; i < 16; ++i) acc[i] = 0.f;
    if (useLds) {
        const int* wc = &wcsr[wave][0];
        unsigned char* stg = &sbuf[wave][0];
        int k = be.x - wstart, kend = be.y - wstart;
        // 4-deep async batches: issue 4 edges/group as global_load_lds (no
        // VGPR cost), drain vmcnt, accumulate from LDS. Ascending edge
        // order -> bitwise-identical result.
        while (__any(k < kend)) {
#pragma unroll
            for (int j = 0; j < 4; ++j) {
                if (k + j < kend) {
                    int src = wc[k + j];
                    glds16(xq + ((size_t)src << 6) + (sub << 4),
                           stg + j * 1024);
                }
            }
            asm volatile("s_waitcnt vmcnt(0)" ::: "memory");
#pragma unroll
            for (int j = 0; j < 4; ++j) {
                if (k + j < kend) {
                    uint4 a = *(const uint4*)(stg + j * 1024 + (lane << 4));
                    ACCQ(a);
                }
            }
            k += 4;
        }
    } else {  // fallback: global csr (window overflow — statistically never)
        int k = be.x, kend = be.y;
        for (; k + 1 < kend; k += 2) {
            int s0 = csr[k], s1 = csr[k + 1];
            uint4 a = ((const uint4*)(xq + ((size_t)s0 << 6)))[sub];
            uint4 b = ((const uint4*)(xq + ((size_t)s1 << 6)))[sub];
            ACCQ(a); ACCQ(b);
        }
        if (k < kend) {
            int s0 = csr[k];
            uint4 a = ((const uint4*)(xq + ((size_t)s0 << 6)))[sub];
            ACCQ(a);
        }
    }
    // mh view overlays the stage region (gather fully consumed above)
    unsigned short (*mh)[72] = (unsigned short (*)[72])&sbuf[wave][0];
    {
        float rd = 1.0f / fmaxf((float)(be.y - be.x), 1.0f);
        uint4 o0, o1;
        o0.x = f2bf(acc[0] * rd) | (f2bf(acc[1] * rd) << 16);
        o0.y = f2bf(acc[2] * rd) | (f2bf(acc[3] * rd) << 16);
        o0.z = f2bf(acc[4] * rd) | (f2bf(acc[5] * rd) << 16);
        o0.w = f2bf(acc[6] * rd) | (f2bf(acc[7] * rd) << 16);
        o1.x = f2bf(acc[8] * rd) | (f2bf(acc[9] * rd) << 16);
        o1.y = f2bf(acc[10] * rd) | (f2bf(acc[11] * rd) << 16);
        o1.z = f2bf(acc[12] * rd) | (f2bf(acc[13] * rd) << 16);
        o1.w = f2bf(acc[14] * rd) | (f2bf(acc[15] * rd) << 16);
        *(uint4*)&mh[grp][sub * 16] = o0;      // feats sub*16..+7
        *(uint4*)&mh[grp][sub * 16 + 8] = o1;  // feats sub*16+8..+15
    }
    // same-wave LDS write->read: lockstep, lgkmcnt handled by compiler

    // ---- A fragments: [mean | x], K = 128 ----
    const short8* bfr = (const short8*)bimg;
    short8 afr0 = *(const short8*)&mh[m][qd * 8];
    short8 afr1 = *(const short8*)&mh[m][32 + qd * 8];

    // ---- layer 1: 4 col-blocks x 4 K-steps; h overwrites mean buffer ----
#pragma unroll
    for (int nb = 0; nb < 4; ++nb) {
        f32x4 c = {0.f, 0.f, 0.f, 0.f};
        c = mfma16(afr0, bfr[nb * 64 + lane], c);
        c = mfma16(afr1, bfr[(4 + nb) * 64 + lane], c);
        c = mfma16(afr2, bfr[(8 + nb) * 64 + lane], c);
        c = mfma16(afr3, bfr[(12 + nb) * 64 + lane], c);
        int col = nb * 16 + m;
        float bb = b1[col];
#pragma unroll
        for (int r = 0; r < 4; ++r) {
            float hv = fmaxf(c[r] + bb, 0.0f);
            mh[qd * 4 + r][col] = (unsigned short)f2bf(hv);
        }
    }

    // ---- layer 2 ----
    short8 ha0 = *(const short8*)&mh[m][qd * 8];
    short8 ha1 = *(const short8*)&mh[m][32 + qd * 8];
    f32x4 pc = {0.f, 0.f, 0.f, 0.f}, qc = {0.f, 0.f, 0.f, 0.f};
    pc = mfma16(ha0, bfr[16 * 64 + lane], pc);
    pc = mfma16(ha1, bfr[18 * 64 + lane], pc);
    qc = mfma16(ha0, bfr[17 * 64 + lane], qc);
    qc = mfma16(ha1, bfr[19 * 64 + lane], qc);
    float b2v = b2[m];
#pragma unroll
    for (int r = 0; r < 4; ++r) {
        int nd = nodebase + qd * 4 + r;
        if (nd < N) {
            p[(size_t)nd * 16 + m] = (unsigned short)f2bf(pc[r]);
            q[(size_t)nd * 16 + m] = qc[r] + b2v;
        }
    }
}

// ---- K4: async-DMA gather p + mean + add + 4-lane log_softmax ----
__global__ __launch_bounds__(256) void finalk(const unsigned short* __restrict__ p,
                                              const int2* __restrict__ rowse,
                                              const int* __restrict__ csr,
                                              float* q, int N) {  // q in/out
    __shared__ __align__(16) unsigned char sbuf[4][4096];  // 16 KB stage
    __shared__ int wcsr[4][WCAP];                          // 8 KB windows
    int t = threadIdx.x;
    int wave = t >> 6, lane = t & 63;
    int grp = lane >> 2, sub = lane & 3;  // 16 node-groups x 4 feature-lanes
    int nodebase = blockIdx.x * 64 + wave * 16;
    int node = nodebase + grp;
    int2 be = (node < N) ? rowse[node] : make_int2(0, 0);

    // stage wave csr window (all lanes participate before any exit)
    int wstart = 0, wlen = 0;
    if (nodebase < N) {
        int ln = min(nodebase + 15, N - 1);
        wstart = rowse[nodebase].x;
        wlen = rowse[ln].y - wstart;
    }
    bool useLds = (wlen <= WCAP);
    if (useLds) {
        for (int i = lane; i < wlen; i += 64) wcsr[wave][i] = csr[wstart + i];
    }
    if (node >= N) return;  // whole 4-lane group exits together

    // hoist the independent self-term read above the gather (overlaps latency)
    float4 qv = ((const float4*)(q + ((size_t)node << 4)))[sub];
    float a0 = 0.f, a1 = 0.f, a2 = 0.f, a3 = 0.f;
    if (useLds) {
        const int* wc = &wcsr[wave][0];
        unsigned char* stg = &sbuf[wave][0];
        int rbase = grp << 6;  // group's 64B (2 p-rows) region within a slot
        int k = be.x - wstart, kend = be.y - wstart;
        // 8 edges/group per batch: slot j holds edges k+2j, k+2j+1 (32B
        // rows; lane pairs load the 16B halves). Ascending order kept.
        while (__any(k < kend)) {
#pragma unroll
            for (int j = 0; j < 4; ++j) {
                int e = k + 2 * j + (sub >> 1);
                if (e < kend) {
                    int src = wc[e];
                    glds16(p + ((size_t)src << 4) + ((sub & 1) << 3),
                           stg + j * 1024);
                }
            }
            asm volatile("s_waitcnt vmcnt(0)" ::: "memory");
#pragma unroll
            for (int j = 0; j < 4; ++j) {
                if (k + 2 * j < kend) {  // edge 1 of slot j
                    uint2 r = *(const uint2*)(stg + j * 1024 + rbase + sub * 8);
                    ACC2(r.x, a0, a1);  ACC2(r.y, a2, a3);
                }
                if (k + 2 * j + 1 < kend) {  // edge 2 of slot j
                    uint2 r = *(const uint2*)(stg + j * 1024 + rbase + 32 + sub * 8);
                    ACC2(r.x, a0, a1);  ACC2(r.y, a2, a3);
                }
            }
            k += 8;
        }
    } else {
        int k = be.x, kend = be.y;
        for (; k + 1 < kend; k += 2) {
            int s0 = csr[k], s1 = csr[k + 1];
            uint2 rA = *(const uint2*)(p + ((size_t)s0 << 4) + (sub << 2));
            uint2 rB = *(const uint2*)(p + ((size_t)s1 << 4) + (sub << 2));
            ACC2(rA.x, a0, a1);  ACC2(rA.y, a2, a3);
            ACC2(rB.x, a0, a1);  ACC2(rB.y, a2, a3);
        }
        if (k < kend) {
            int s0 = csr[k];
            uint2 rA = *(const uint2*)(p + ((size_t)s0 << 4) + (sub << 2));
            ACC2(rA.x, a0, a1);  ACC2(rA.y, a2, a3);
        }
    }
    float rd = 1.0f / fmaxf((float)(be.y - be.x), 1.0f);
    float4 v = {a0 * rd + qv.x, a1 * rd + qv.y, a2 * rd + qv.z, a3 * rd + qv.w};
    float mm = fmaxf(fmaxf(v.x, v.y), fmaxf(v.z, v.w));
    mm = fmaxf(mm, __shfl_xor(mm, 1));
    mm = fmaxf(mm, __shfl_xor(mm, 2));
    float s = __expf(v.x - mm) + __expf(v.y - mm) + __expf(v.z - mm) + __expf(v.w - mm);
    s += __shfl_xor(s, 1);
    s += __shfl_xor(s, 2);
    float ls = __logf(s);
    float4 o = {v.x - mm - ls, v.y - mm - ls, v.z - mm - ls, v.w - mm - ls};
    ((float4*)(q + ((size_t)node << 4)))[sub] = o;
}

extern "C" void kernel_launch(void* const* d_in, const int* in_sizes, int n_in,
                              void* d_out, int out_size, void* d_ws, size_t ws_size,
                              hipStream_t stream) {
    const float* x   = (const float*)d_in[0];
    const int* ei    = (const int*)d_in[1];
    const float* W1l = (const float*)d_in[2];
    const float* W1r = (const float*)d_in[3];
    const float* b1  = (const float*)d_in[4];
    const float* W2l = (const float*)d_in[5];
    const float* W2r = (const float*)d_in[6];
    const float* b2  = (const float*)d_in[7];
    const int N = in_sizes[0] / 64;
    const int E = in_sizes[1] / 2;
    const int nbk = (N + BK - 1) / BK;  // 391 for N=100000

    // workspace layout (NO overlays — partprep_k writes part/xb/xq
    // concurrently):
    //   bcnt(2K) | rowse(N*8) | csr(nbk*CAP*4) | bimg(20K) | p(N*32) |
    //   part(nbk*CAP*4) | xb(N*128) | xq(N*64)   total ~40 MB
    int*  bcnt  = (int*)d_ws;                            // NBMAX ints
    int2* rowse = (int2*)(bcnt + NBMAX);                 // N
    int*  csr   = (int*)(rowse + N);                     // nbk*CAP
    unsigned short* bimg = (unsigned short*)(csr + (size_t)nbk * CAP);
    unsigned short* p    = bimg + 20 * 64 * 8;           // N*16
    unsigned* part = (unsigned*)(p + (size_t)N * 16);    // nbk*CAP
    unsigned short* xb = (unsigned short*)(part + (size_t)nbk * CAP);  // N*64
    unsigned char* xq = (unsigned char*)(xb + (size_t)N * 64);         // N*64
    float* q = (float*)d_out;                            // N*16 (temp q, then out)

    hipMemsetAsync(bcnt, 0, NBMAX * sizeof(int), stream);

    const int pblocks = (E + TILE - 1) / TILE;
    const int xblocks = (N * 64 + 4095) / 4096;  // 512 thr x 8 elems
    partprep_k<<<pblocks + xblocks + 3, 512, 0, stream>>>(
        ei, bcnt, part, E, pblocks, x, xb, xq, N * 64, W1l, W1r, W2l, W2r,
        bimg, xblocks);
    csr_k<<<nbk, 256, 0, stream>>>(part, bcnt, csr, rowse, N);
    l1x<<<(N + 63) / 64, 256, 0, stream>>>(xb, xq, rowse, csr, bimg, b1, b2,
                                           p, q, N);
    finalk<<<(N + 63) / 64, 256, 0, stream>>>(p, rowse, csr, q, N);
}